// Round 5
// baseline (354.713 us; speedup 1.0000x reference)
//
#include <hip/hip_runtime.h>
#include <stdint.h>
#include <math.h>

// ---------------------------------------------------------------------------
// HardNegativeMiner round 5: decompose. k_gumbel writes all 54.5M gumbels
// (pure VALU, no barriers, ~95% VALUBusy) with diagonal pre-masked to -inf;
// k_prep pre-normalizes rows so the split-bf16 GEMM produces sim directly;
// k_main's epilogue is then load-g + fmaf + cmp (6 insts/candidate), fits
// (256,4) without spill. Fallback to round-4 fused path if ws too small.
// PRNG chain (partitionable threefry) verified bit-exact in rounds 1-4.
// ---------------------------------------------------------------------------
#define BN 16384   // batch
#define DK 256     // dim
#define NH 3276    // int(16384*0.2)
#define NJB 26     // j-strips of 128
#define NCB 128    // c-blocks of 128

typedef __attribute__((ext_vector_type(8))) short short8;
typedef __attribute__((ext_vector_type(4))) short short4v;
typedef __attribute__((ext_vector_type(4))) float f32x4;

__host__ __device__ __forceinline__ void tf2x32(uint32_t k0, uint32_t k1,
                                                uint32_t c0, uint32_t c1,
                                                uint32_t& o0, uint32_t& o1) {
  uint32_t ks2 = 0x1BD11BDAu ^ k0 ^ k1;
  uint32_t x0 = c0 + k0, x1 = c1 + k1;
#define RR(d) { x0 += x1; x1 = (x1 << d) | (x1 >> (32 - d)); x1 ^= x0; }
  RR(13) RR(15) RR(26) RR(6)   x0 += k1;  x1 += ks2 + 1u;
  RR(17) RR(29) RR(16) RR(24)  x0 += ks2; x1 += k0  + 2u;
  RR(13) RR(15) RR(26) RR(6)   x0 += k0;  x1 += k1  + 3u;
  RR(17) RR(29) RR(16) RR(24)  x0 += k1;  x1 += ks2 + 4u;
  RR(13) RR(15) RR(26) RR(6)   x0 += ks2; x1 += k0  + 5u;
#undef RR
  o0 = x0; o1 = x1;
}

__device__ __forceinline__ uint32_t rand32_at(uint32_t k0, uint32_t k1, uint32_t p) {
  uint32_t x0, x1; tf2x32(k0, k1, 0u, p, x0, x1);
  return x0 ^ x1;
}

__device__ __forceinline__ float unif01_from_bits(uint32_t bits) {
  return __uint_as_float((bits >> 9) | 0x3f800000u) - 1.0f;
}

// gumbel at flat counter p: -log(-log(max(u, tiny))), fast v_log_f32 path
__device__ __forceinline__ float gumbel_at(uint32_t k0, uint32_t k1, uint32_t p) {
  uint32_t bits = rand32_at(k0, k1, p);
  float f = unif01_from_bits(bits);
  float u = fmaxf(f, 1.17549435e-38f);             // minval = finfo(f32).tiny
  float t = __log2f(u) * (-0.69314718055994531f);  // -ln(u) > 0
  return __log2f(t) * (-0.69314718055994531f);     // -ln(t)
}

// monotonic float->u32; pack (value, ~col): max => larger val, tie => smaller col
__device__ __forceinline__ unsigned long long packvc(float v, uint32_t c) {
  uint32_t u = __float_as_uint(v);
  u ^= ((int32_t)u < 0) ? 0xFFFFFFFFu : 0x80000000u;
  return ((unsigned long long)u << 32) | (unsigned long long)(~c);
}

// 16-byte global -> LDS async DMA. LDS dest is wave-uniform base + lane*16.
__device__ __forceinline__ void glds16(const unsigned short* g, short* l) {
  __builtin_amdgcn_global_load_lds(
      (const __attribute__((address_space(1))) void*)g,
      (__attribute__((address_space(3))) void*)l, 16, 0, 0);
}

// ---------------------------------------------------------------------------
// Fused: row inv-norms + split-bf16 copy (optionally pre-scaled by inv_norm
// so GEMM acc == sim) + src_idx/best setup.
__global__ __launch_bounds__(256) void k_prep(const float* __restrict__ z,
                                              float* __restrict__ inv_norm,
                                              unsigned short* __restrict__ zh,
                                              unsigned short* __restrict__ zl,
                                              int* __restrict__ src_idx,
                                              unsigned long long* __restrict__ best,
                                              uint32_t k20, uint32_t k21,
                                              int normalize) {
  int b = blockIdx.x, t = threadIdx.x;
  if (b < BN / 4) {
    int row = b * 4 + (t >> 6), lane = t & 63;
    float4 v = *(const float4*)&z[row * DK + lane * 4];
    float ss = v.x * v.x + v.y * v.y + v.z * v.z + v.w * v.w;
#pragma unroll
    for (int off = 32; off; off >>= 1) ss += __shfl_xor(ss, off, 64);
    float inv = 1.0f / fmaxf(sqrtf(ss), 1e-12f);
    if (lane == 0) inv_norm[row] = inv;
    float s = normalize ? inv : 1.0f;
    float f[4] = {v.x * s, v.y * s, v.z * s, v.w * s};
    short4v h, l;
#pragma unroll
    for (int i = 0; i < 4; ++i) {
      uint32_t u = __float_as_uint(f[i]);
      h[i] = (short)(u >> 16);
      float r = f[i] - __uint_as_float(u & 0xFFFF0000u);
      l[i] = (short)(__float_as_uint(r) >> 16);
    }
    *(short4v*)&zh[row * DK + lane * 4] = h;
    *(short4v*)&zl[row * DK + lane * 4] = l;
  } else {
    int i = (b - BN / 4) * 256 + t;
    if (i < NH) {
      uint32_t bits = rand32_at(k20, k21, (uint32_t)i);
      src_idx[i] = (int)(bits & (uint32_t)(BN - 1));  // randint span 2^14
      best[i] = 0ull;                                 // identity for packvc keys
    }
  }
}

// ---------------------------------------------------------------------------
// Pure-VALU gumbel generation: g[gj][c] = -log(-log(u(gj*BN+c))), with the
// diagonal (c == src_idx[gj]) pre-masked to -inf. 8 consecutive c per thread.
__global__ __launch_bounds__(256) void k_gumbel(const int* __restrict__ src_idx,
                                                float* __restrict__ g,
                                                uint32_t kt0, uint32_t kt1) {
  uint32_t p0 = (uint32_t)(blockIdx.x * 256 + threadIdx.x) * 8u;
  int gj = (int)(p0 >> 14);
  int c0 = (int)(p0 & 16383u);
  int s = src_idx[min(gj, NH - 1)];
  float o[8];
#pragma unroll
  for (int i = 0; i < 8; ++i) {
    float gv = gumbel_at(kt0, kt1, p0 + (uint32_t)i);
    o[i] = (c0 + i == s) ? -INFINITY : gv;
  }
  float4* dst = (float4*)&g[p0];
  dst[0] = (float4){o[0], o[1], o[2], o[3]};
  dst[1] = (float4){o[4], o[5], o[6], o[7]};
}

// ---------------------------------------------------------------------------
// Lean k_main: 128x128 block tile, 4 waves of 64x64, K=256 in 8 chunks of 32.
// acc == sim (pre-normalized inputs). Epilogue: tot = fmaf(sim,10,g[gj][c]).
__global__ __launch_bounds__(256, 4) void k_main_lean(const unsigned short* __restrict__ zh,
                                                      const unsigned short* __restrict__ zl,
                                                      const float* __restrict__ g,
                                                      const int* __restrict__ src_idx,
                                                      unsigned long long* __restrict__ best) {
  __shared__ __align__(16) short As_hi[128 * 32];
  __shared__ __align__(16) short As_lo[128 * 32];
  __shared__ __align__(16) short Bs_hi[128 * 32];
  __shared__ __align__(16) short Bs_lo[128 * 32];

  // XCD-aware swizzle: XCD x owns c-blocks [16x, 16x+16) -> 2 MB B-set per L2
  const int flat = blockIdx.x;                 // 3328 = 8 * (16 * 26)
  const int xcd = flat & 7, slot = flat >> 3;  // slot in [0, 416)
  const int c_base = (xcd * 16 + (slot & 15)) * 128;
  const int j_base = (slot >> 4) * 128;

  const int t = threadIdx.x;
  const int lane = t & 63, w = t >> 6;

  // staging: wave w DMAs chunks {2w, 2w+1} (16 rows x 1 KB each) of all 4 tiles
  const int r0 = w * 32 + (lane >> 2);
  const int r1 = r0 + 16;
  const int u0 = (lane & 3) ^ ((r0 >> 1) & 3);
  const int u1 = (lane & 3) ^ ((r1 >> 1) & 3);
  const int ga0 = src_idx[min(j_base + r0, NH - 1)];
  const int ga1 = src_idx[min(j_base + r1, NH - 1)];
  const uint32_t offA0 = (uint32_t)(ga0 * DK + u0 * 8);
  const uint32_t offA1 = (uint32_t)(ga1 * DK + u1 * 8);
  const uint32_t offB0 = (uint32_t)((c_base + r0) * DK + u0 * 8);
  const uint32_t offB1 = (uint32_t)((c_base + r1) * DK + u1 * 8);
  short* dA  = &As_hi[w * 1024];
  short* dAl = &As_lo[w * 1024];
  short* dB  = &Bs_hi[w * 1024];
  short* dBl = &Bs_lo[w * 1024];

  const int cl = lane & 15, q = lane >> 4;
  const int mb = (w >> 1) * 64 + cl;
  const int nb = (w & 1) * 64 + cl;

  f32x4 acc[4][4];
#pragma unroll
  for (int mt = 0; mt < 4; ++mt)
#pragma unroll
    for (int nt = 0; nt < 4; ++nt) acc[mt][nt] = (f32x4){0.f, 0.f, 0.f, 0.f};

#pragma unroll
  for (int kc = 0; kc < 8; ++kc) {
    const int ko = kc * 32;
    glds16(zh + offA0 + ko, dA);
    glds16(zh + offA1 + ko, dA + 512);
    glds16(zl + offA0 + ko, dAl);
    glds16(zl + offA1 + ko, dAl + 512);
    glds16(zh + offB0 + ko, dB);
    glds16(zh + offB1 + ko, dB + 512);
    glds16(zl + offB0 + ko, dBl);
    glds16(zl + offB1 + ko, dBl + 512);
    __syncthreads();

    short8 bh[4], bl[4];
#pragma unroll
    for (int nt = 0; nt < 4; ++nt) {
      int row = nb + nt * 16;
      int off = row * 32 + (q ^ ((row >> 1) & 3)) * 8;
      bh[nt] = *(const short8*)&Bs_hi[off];
      bl[nt] = *(const short8*)&Bs_lo[off];
    }
#pragma unroll
    for (int mt = 0; mt < 4; ++mt) {
      int row = mb + mt * 16;
      int off = row * 32 + (q ^ ((row >> 1) & 3)) * 8;
      short8 ah = *(const short8*)&As_hi[off];
      short8 al = *(const short8*)&As_lo[off];
#pragma unroll
      for (int nt = 0; nt < 4; ++nt) {
        acc[mt][nt] = __builtin_amdgcn_mfma_f32_16x16x32_bf16(ah, bh[nt], acc[mt][nt], 0, 0, 0);
        acc[mt][nt] = __builtin_amdgcn_mfma_f32_16x16x32_bf16(ah, bl[nt], acc[mt][nt], 0, 0, 0);
        acc[mt][nt] = __builtin_amdgcn_mfma_f32_16x16x32_bf16(al, bh[nt], acc[mt][nt], 0, 0, 0);
      }
    }
    __syncthreads();
  }

  // ---- lean epilogue: tot = fmaf(sim, 10, g); argmax over wave's 64 cols ----
  const int q4 = (lane >> 4) * 4;
  const int coff = c_base + (w & 1) * 64;
  const int roff = j_base + (w >> 1) * 64;
#pragma unroll
  for (int mt = 0; mt < 4; ++mt)
#pragma unroll
    for (int r = 0; r < 4; ++r) {
      int gj = roff + mt * 16 + q4 + r;
      const float* grow = g + (size_t)gj * BN + coff + cl;
      float bv = -INFINITY; uint32_t bc = 0;
#pragma unroll
      for (int nt = 0; nt < 4; ++nt) {
        float gv = grow[nt * 16];
        float tot = fmaf(acc[mt][nt][r], 10.0f, gv);   // logits = sim / 0.1
        if (tot > bv) { bv = tot; bc = (uint32_t)(coff + nt * 16 + cl); }
      }
      unsigned long long key = packvc(bv, bc);
#pragma unroll
      for (int off = 1; off <= 8; off <<= 1) {
        unsigned long long o = __shfl_xor(key, off, 64);
        if (o > key) key = o;
      }
      if (cl == 0 && gj < NH) atomicMax(&best[gj], key);
    }
}

// ---------------------------------------------------------------------------
// Fallback fused k_main (round 4, unchanged): used when ws too small for g.
__global__ __launch_bounds__(256, 3) void k_main_fused(const unsigned short* __restrict__ zh,
                                                       const unsigned short* __restrict__ zl,
                                                       const float* __restrict__ inv_norm,
                                                       const int* __restrict__ src_idx,
                                                       unsigned long long* __restrict__ best,
                                                       uint32_t kt0, uint32_t kt1) {
  __shared__ __align__(16) short As_hi[128 * 32];
  __shared__ __align__(16) short As_lo[128 * 32];
  __shared__ __align__(16) short Bs_hi[128 * 32];
  __shared__ __align__(16) short Bs_lo[128 * 32];
  const int flat = blockIdx.x;
  const int xcd = flat & 7, slot = flat >> 3;
  const int c_base = (xcd * 16 + (slot & 15)) * 128;
  const int j_base = (slot >> 4) * 128;
  const int t = threadIdx.x;
  const int lane = t & 63, w = t >> 6;
  const int r0 = w * 32 + (lane >> 2);
  const int r1 = r0 + 16;
  const int u0 = (lane & 3) ^ ((r0 >> 1) & 3);
  const int u1 = (lane & 3) ^ ((r1 >> 1) & 3);
  const int ga0 = src_idx[min(j_base + r0, NH - 1)];
  const int ga1 = src_idx[min(j_base + r1, NH - 1)];
  const uint32_t offA0 = (uint32_t)(ga0 * DK + u0 * 8);
  const uint32_t offA1 = (uint32_t)(ga1 * DK + u1 * 8);
  const uint32_t offB0 = (uint32_t)((c_base + r0) * DK + u0 * 8);
  const uint32_t offB1 = (uint32_t)((c_base + r1) * DK + u1 * 8);
  short* dA  = &As_hi[w * 1024];
  short* dAl = &As_lo[w * 1024];
  short* dB  = &Bs_hi[w * 1024];
  short* dBl = &Bs_lo[w * 1024];
  const int cl = lane & 15, q = lane >> 4;
  const int mb = (w >> 1) * 64 + cl;
  const int nb = (w & 1) * 64 + cl;
  f32x4 acc[4][4];
#pragma unroll
  for (int mt = 0; mt < 4; ++mt)
#pragma unroll
    for (int nt = 0; nt < 4; ++nt) acc[mt][nt] = (f32x4){0.f, 0.f, 0.f, 0.f};
#pragma unroll
  for (int kc = 0; kc < 8; ++kc) {
    const int ko = kc * 32;
    glds16(zh + offA0 + ko, dA);
    glds16(zh + offA1 + ko, dA + 512);
    glds16(zl + offA0 + ko, dAl);
    glds16(zl + offA1 + ko, dAl + 512);
    glds16(zh + offB0 + ko, dB);
    glds16(zh + offB1 + ko, dB + 512);
    glds16(zl + offB0 + ko, dBl);
    glds16(zl + offB1 + ko, dBl + 512);
    __syncthreads();
    short8 bh[4], bl[4];
#pragma unroll
    for (int nt = 0; nt < 4; ++nt) {
      int row = nb + nt * 16;
      int off = row * 32 + (q ^ ((row >> 1) & 3)) * 8;
      bh[nt] = *(const short8*)&Bs_hi[off];
      bl[nt] = *(const short8*)&Bs_lo[off];
    }
#pragma unroll
    for (int mt = 0; mt < 4; ++mt) {
      int row = mb + mt * 16;
      int off = row * 32 + (q ^ ((row >> 1) & 3)) * 8;
      short8 ah = *(const short8*)&As_hi[off];
      short8 al = *(const short8*)&As_lo[off];
#pragma unroll
      for (int nt = 0; nt < 4; ++nt) {
        acc[mt][nt] = __builtin_amdgcn_mfma_f32_16x16x32_bf16(ah, bh[nt], acc[mt][nt], 0, 0, 0);
        acc[mt][nt] = __builtin_amdgcn_mfma_f32_16x16x32_bf16(ah, bl[nt], acc[mt][nt], 0, 0, 0);
        acc[mt][nt] = __builtin_amdgcn_mfma_f32_16x16x32_bf16(al, bh[nt], acc[mt][nt], 0, 0, 0);
      }
    }
    __syncthreads();
  }
  const int q4 = (lane >> 4) * 4;
  const int coff = c_base + (w & 1) * 64;
  const int roff = j_base + (w >> 1) * 64;
  float invc[4]; int colg[4];
#pragma unroll
  for (int nt = 0; nt < 4; ++nt) {
    colg[nt] = coff + nt * 16 + cl;
    invc[nt] = inv_norm[colg[nt]];
  }
#pragma unroll
  for (int mt = 0; mt < 4; ++mt)
#pragma unroll
    for (int r = 0; r < 4; ++r) {
      int gj = roff + mt * 16 + q4 + r;
      int s = src_idx[min(gj, NH - 1)];
      float invs = inv_norm[s];
      uint32_t pbase = (uint32_t)gj * (uint32_t)BN;
      float bv = -INFINITY; uint32_t bc = 0;
#pragma unroll
      for (int nt = 0; nt < 4; ++nt) {
        float sim = acc[mt][nt][r] * invs * invc[nt];
        float gmb = gumbel_at(0u, 0u, 0u);  // placeholder to keep signature; real below
        (void)gmb;
        float gv = gumbel_at(kt0, kt1, pbase + (uint32_t)colg[nt]);
        float tot = fmaf(sim, 10.0f, gv);
        if (colg[nt] == s) tot = -INFINITY;
        if (tot > bv) { bv = tot; bc = (uint32_t)colg[nt]; }
      }
      unsigned long long key = packvc(bv, bc);
#pragma unroll
      for (int off = 1; off <= 8; off <<= 1) {
        unsigned long long o = __shfl_xor(key, off, 64);
        if (o > key) key = o;
      }
      if (cl == 0 && gj < NH) atomicMax(&best[gj], key);
    }
}

__global__ __launch_bounds__(64) void k_out(const float* __restrict__ z,
                                            const int* __restrict__ src_idx,
                                            const unsigned long long* __restrict__ best,
                                            float* __restrict__ out,
                                            uint32_t ka0, uint32_t ka1) {
  int j = blockIdx.x;
  int lane = threadIdx.x;
  int s = src_idx[j];
  int tgt = (int)(~((uint32_t)(best[j] & 0xFFFFFFFFull)));
  uint32_t bits = rand32_at(ka0, ka1, (uint32_t)j);
  float alpha = unif01_from_bits(bits) * 0.5f;   // uniform * MIX_ALPHA
  float om = 1.0f - alpha;
  float4 a = *(const float4*)&z[s * DK + lane * 4];
  float4 b = *(const float4*)&z[tgt * DK + lane * 4];
  float4 o;
  o.x = alpha * a.x + om * b.x;
  o.y = alpha * a.y + om * b.y;
  o.z = alpha * a.z + om * b.z;
  o.w = alpha * a.w + om * b.w;
  *(float4*)&out[j * DK + lane * 4] = o;
}

// ---------------------------------------------------------------------------
extern "C" void kernel_launch(void* const* d_in, const int* in_sizes, int n_in,
                              void* d_out, int out_size, void* d_ws, size_t ws_size,
                              hipStream_t stream) {
  const float* z = (const float*)d_in[0];
  float* out = (float*)d_out;
  char* ws = (char*)d_ws;
  // ws layout:
  int*                src_idx  = (int*)(ws);                        // 16 KB
  unsigned long long* best     = (unsigned long long*)(ws + 16384); // 32 KB
  float*              inv_norm = (float*)(ws + 49152);              // 64 KB
  unsigned short*     zh       = (unsigned short*)(ws + 131072);    // 8.39 MB
  unsigned short*     zl       = (unsigned short*)(ws + 131072 + 8388608);
  float*              gbuf     = (float*)(ws + 131072 + 2 * 8388608);
  const size_t need_g = 131072 + 2 * 8388608 + (size_t)3328 * BN * 4; // ~235 MB
  const bool use_g = ws_size >= need_g;

  // host-side threefry key derivation (partitionable scheme, verified round 1)
  uint32_t r0 = 0u, r1 = 42u;
  uint32_t ks0, ks1, kt0, kt1, ka0, ka1, k20, k21;
  tf2x32(r0, r1, 0u, 0u, ks0, ks1);   // k_src   = split(root,3)[0]
  tf2x32(r0, r1, 0u, 1u, kt0, kt1);   // k_tgt   = split(root,3)[1]
  tf2x32(r0, r1, 0u, 2u, ka0, ka1);   // k_alpha = split(root,3)[2]
  tf2x32(ks0, ks1, 0u, 1u, k20, k21); // split(k_src,2)[1] (randint lower bits)

  k_prep<<<dim3(BN / 4 + (NH + 255) / 256), dim3(256), 0, stream>>>(
      z, inv_norm, zh, zl, src_idx, best, k20, k21, use_g ? 1 : 0);
  if (use_g) {
    k_gumbel<<<dim3(3328 * BN / (256 * 8)), dim3(256), 0, stream>>>(src_idx, gbuf, kt0, kt1);
    k_main_lean<<<dim3(NCB * NJB), dim3(256), 0, stream>>>(zh, zl, gbuf, src_idx, best);
  } else {
    k_main_fused<<<dim3(NCB * NJB), dim3(256), 0, stream>>>(zh, zl, inv_norm, src_idx, best, kt0, kt1);
  }
  k_out<<<dim3(NH), dim3(64), 0, stream>>>(z, src_idx, best, out, ka0, ka1);
}

// Round 6
// 263.895 us; speedup vs baseline: 1.3441x; 1.3441x over previous
//
#include <hip/hip_runtime.h>
#include <stdint.h>
#include <math.h>

// ---------------------------------------------------------------------------
// HardNegativeMiner round 6: revert to round-4 fused structure (g-buffer
// decomposition regressed: 218 MB HBM round-trip + re-spill). Changes vs r4:
//  1. threefry rotates via v_alignbit_b32 (1 inst vs 3) -> ~30% fewer VALU
//     insts in the dominant gumbel epilogue.
//  2. zh/zl pre-normalized by inv row norm (HW-verified in r5) -> epilogue is
//     acc==sim, drops inv_norm loads and 2 muls/candidate.
// PRNG chain (partitionable threefry) verified bit-exact in rounds 1-5.
// Reg budget: (256,3) -> 168; r4 measured 148 used, no spill.
// ---------------------------------------------------------------------------
#define BN 16384   // batch
#define DK 256     // dim
#define NH 3276    // int(16384*0.2)
#define NJB 26     // j-strips of 128
#define NCB 128    // c-blocks of 128

typedef __attribute__((ext_vector_type(8))) short short8;
typedef __attribute__((ext_vector_type(4))) short short4v;
typedef __attribute__((ext_vector_type(4))) float f32x4;

__host__ __device__ __forceinline__ uint32_t rotl32(uint32_t x, int d) {
#ifdef __HIP_DEVICE_COMPILE__
  return __builtin_amdgcn_alignbit(x, x, 32 - d);  // v_alignbit_b32: rotr(x,32-d)
#else
  return (x << d) | (x >> (32 - d));
#endif
}

__host__ __device__ __forceinline__ void tf2x32(uint32_t k0, uint32_t k1,
                                                uint32_t c0, uint32_t c1,
                                                uint32_t& o0, uint32_t& o1) {
  uint32_t ks2 = 0x1BD11BDAu ^ k0 ^ k1;
  uint32_t x0 = c0 + k0, x1 = c1 + k1;
#define RR(d) { x0 += x1; x1 = rotl32(x1, d); x1 ^= x0; }
  RR(13) RR(15) RR(26) RR(6)   x0 += k1;  x1 += ks2 + 1u;
  RR(17) RR(29) RR(16) RR(24)  x0 += ks2; x1 += k0  + 2u;
  RR(13) RR(15) RR(26) RR(6)   x0 += k0;  x1 += k1  + 3u;
  RR(17) RR(29) RR(16) RR(24)  x0 += k1;  x1 += ks2 + 4u;
  RR(13) RR(15) RR(26) RR(6)   x0 += ks2; x1 += k0  + 5u;
#undef RR
  o0 = x0; o1 = x1;
}

__device__ __forceinline__ uint32_t rand32_at(uint32_t k0, uint32_t k1, uint32_t p) {
  uint32_t x0, x1; tf2x32(k0, k1, 0u, p, x0, x1);
  return x0 ^ x1;
}

__device__ __forceinline__ float unif01_from_bits(uint32_t bits) {
  return __uint_as_float((bits >> 9) | 0x3f800000u) - 1.0f;
}

// gumbel at flat counter p: -log(-log(max(u, tiny))), fast v_log_f32 path
__device__ __forceinline__ float gumbel_at(uint32_t k0, uint32_t k1, uint32_t p) {
  uint32_t bits = rand32_at(k0, k1, p);
  float f = unif01_from_bits(bits);
  float u = fmaxf(f, 1.17549435e-38f);             // minval = finfo(f32).tiny
  float t = __log2f(u) * (-0.69314718055994531f);  // -ln(u) > 0
  return __log2f(t) * (-0.69314718055994531f);     // -ln(t)
}

// monotonic float->u32; pack (value, ~col): max => larger val, tie => smaller col
__device__ __forceinline__ unsigned long long packvc(float v, uint32_t c) {
  uint32_t u = __float_as_uint(v);
  u ^= ((int32_t)u < 0) ? 0xFFFFFFFFu : 0x80000000u;
  return ((unsigned long long)u << 32) | (unsigned long long)(~c);
}

// 16-byte global -> LDS async DMA. LDS dest is wave-uniform base + lane*16.
__device__ __forceinline__ void glds16(const unsigned short* g, short* l) {
  __builtin_amdgcn_global_load_lds(
      (const __attribute__((address_space(1))) void*)g,
      (__attribute__((address_space(3))) void*)l, 16, 0, 0);
}

// ---------------------------------------------------------------------------
// Fused: row inv-norm + split-bf16 copy of z*inv (GEMM acc == sim directly)
// + src_idx/best setup.
__global__ __launch_bounds__(256) void k_prep(const float* __restrict__ z,
                                              unsigned short* __restrict__ zh,
                                              unsigned short* __restrict__ zl,
                                              int* __restrict__ src_idx,
                                              unsigned long long* __restrict__ best,
                                              uint32_t k20, uint32_t k21) {
  int b = blockIdx.x, t = threadIdx.x;
  if (b < BN / 4) {
    int row = b * 4 + (t >> 6), lane = t & 63;
    float4 v = *(const float4*)&z[row * DK + lane * 4];
    float ss = v.x * v.x + v.y * v.y + v.z * v.z + v.w * v.w;
#pragma unroll
    for (int off = 32; off; off >>= 1) ss += __shfl_xor(ss, off, 64);
    float inv = 1.0f / fmaxf(sqrtf(ss), 1e-12f);
    float f[4] = {v.x * inv, v.y * inv, v.z * inv, v.w * inv};
    short4v h, l;
#pragma unroll
    for (int i = 0; i < 4; ++i) {
      uint32_t u = __float_as_uint(f[i]);
      h[i] = (short)(u >> 16);
      float r = f[i] - __uint_as_float(u & 0xFFFF0000u);
      l[i] = (short)(__float_as_uint(r) >> 16);
    }
    *(short4v*)&zh[row * DK + lane * 4] = h;
    *(short4v*)&zl[row * DK + lane * 4] = l;
  } else {
    int i = (b - BN / 4) * 256 + t;
    if (i < NH) {
      uint32_t bits = rand32_at(k20, k21, (uint32_t)i);
      src_idx[i] = (int)(bits & (uint32_t)(BN - 1));  // randint span 2^14
      best[i] = 0ull;                                 // identity for packvc keys
    }
  }
}

// ---------------------------------------------------------------------------
// 128x128 block tile, 4 waves of 64x64, K=256 in 8 chunks of 32.
// LDS rows of 32 shorts; 16B data-unit u stored at u ^ ((row>>1)&3) so
// fragment ds_read_b128 spreads 2-way over bank quads (free); DMA source
// addresses carry the inverse swizzle. Fused threefry-gumbel argmax epilogue.
__global__ __launch_bounds__(256, 3) void k_main(const unsigned short* __restrict__ zh,
                                                 const unsigned short* __restrict__ zl,
                                                 const int* __restrict__ src_idx,
                                                 unsigned long long* __restrict__ best,
                                                 uint32_t kt0, uint32_t kt1) {
  __shared__ __align__(16) short As_hi[128 * 32];
  __shared__ __align__(16) short As_lo[128 * 32];
  __shared__ __align__(16) short Bs_hi[128 * 32];
  __shared__ __align__(16) short Bs_lo[128 * 32];

  // XCD-aware swizzle: XCD x owns c-blocks [16x, 16x+16) -> 2 MB B-set per L2
  const int flat = blockIdx.x;                 // 3328 = 8 * (16 * 26)
  const int xcd = flat & 7, slot = flat >> 3;  // slot in [0, 416)
  const int c_base = (xcd * 16 + (slot & 15)) * 128;
  const int j_base = (slot >> 4) * 128;

  const int t = threadIdx.x;
  const int lane = t & 63, w = t >> 6;

  // staging: wave w DMAs chunks {2w, 2w+1} (16 rows x 1 KB each) of all 4 tiles
  const int r0 = w * 32 + (lane >> 2);
  const int r1 = r0 + 16;
  const int u0 = (lane & 3) ^ ((r0 >> 1) & 3);
  const int u1 = (lane & 3) ^ ((r1 >> 1) & 3);
  const int ga0 = src_idx[min(j_base + r0, NH - 1)];
  const int ga1 = src_idx[min(j_base + r1, NH - 1)];
  const uint32_t offA0 = (uint32_t)(ga0 * DK + u0 * 8);
  const uint32_t offA1 = (uint32_t)(ga1 * DK + u1 * 8);
  const uint32_t offB0 = (uint32_t)((c_base + r0) * DK + u0 * 8);
  const uint32_t offB1 = (uint32_t)((c_base + r1) * DK + u1 * 8);
  short* dA  = &As_hi[w * 1024];  // same offsets valid for all 4 tile buffers
  short* dAl = &As_lo[w * 1024];
  short* dB  = &Bs_hi[w * 1024];
  short* dBl = &Bs_lo[w * 1024];

  // fragment roles (all LDS addresses kc-invariant)
  const int cl = lane & 15, q = lane >> 4;
  const int mb = (w >> 1) * 64 + cl;
  const int nb = (w & 1) * 64 + cl;

  f32x4 acc[4][4];
#pragma unroll
  for (int mt = 0; mt < 4; ++mt)
#pragma unroll
    for (int nt = 0; nt < 4; ++nt) acc[mt][nt] = (f32x4){0.f, 0.f, 0.f, 0.f};

#pragma unroll
  for (int kc = 0; kc < 8; ++kc) {
    const int ko = kc * 32;
    glds16(zh + offA0 + ko, dA);
    glds16(zh + offA1 + ko, dA + 512);
    glds16(zl + offA0 + ko, dAl);
    glds16(zl + offA1 + ko, dAl + 512);
    glds16(zh + offB0 + ko, dB);
    glds16(zh + offB1 + ko, dB + 512);
    glds16(zl + offB0 + ko, dBl);
    glds16(zl + offB1 + ko, dBl + 512);
    __syncthreads();

    short8 bh[4], bl[4];
#pragma unroll
    for (int nt = 0; nt < 4; ++nt) {
      int row = nb + nt * 16;
      int off = row * 32 + (q ^ ((row >> 1) & 3)) * 8;
      bh[nt] = *(const short8*)&Bs_hi[off];
      bl[nt] = *(const short8*)&Bs_lo[off];
    }
#pragma unroll
    for (int mt = 0; mt < 4; ++mt) {
      int row = mb + mt * 16;
      int off = row * 32 + (q ^ ((row >> 1) & 3)) * 8;
      short8 ah = *(const short8*)&As_hi[off];
      short8 al = *(const short8*)&As_lo[off];
#pragma unroll
      for (int nt = 0; nt < 4; ++nt) {
        acc[mt][nt] = __builtin_amdgcn_mfma_f32_16x16x32_bf16(ah, bh[nt], acc[mt][nt], 0, 0, 0);
        acc[mt][nt] = __builtin_amdgcn_mfma_f32_16x16x32_bf16(ah, bl[nt], acc[mt][nt], 0, 0, 0);
        acc[mt][nt] = __builtin_amdgcn_mfma_f32_16x16x32_bf16(al, bh[nt], acc[mt][nt], 0, 0, 0);
      }
    }
    __syncthreads();
  }

  // ---- epilogue: acc==sim; tot = fmaf(sim,10,gumbel); argmax over 64 cols ----
  const int q4 = (lane >> 4) * 4;
  const int coff = c_base + (w & 1) * 64;
  const int roff = j_base + (w >> 1) * 64;
  const uint32_t ccl = (uint32_t)(coff + cl);
#pragma unroll
  for (int mt = 0; mt < 4; ++mt)
#pragma unroll
    for (int r = 0; r < 4; ++r) {
      int gj = roff + mt * 16 + q4 + r;
      int s = src_idx[min(gj, NH - 1)];
      uint32_t pbase = (uint32_t)gj * (uint32_t)BN + ccl;  // + nt*16 per cand
      float bv = -INFINITY; uint32_t bc = 0;
#pragma unroll
      for (int nt = 0; nt < 4; ++nt) {
        uint32_t c = ccl + (uint32_t)(nt * 16);
        float gv = gumbel_at(kt0, kt1, pbase + (uint32_t)(nt * 16));
        float tot = fmaf(acc[mt][nt][r], 10.0f, gv);   // logits = sim / 0.1
        tot = ((int)c == s) ? -INFINITY : tot;         // diagonal mask
        if (tot > bv) { bv = tot; bc = c; }
      }
      unsigned long long key = packvc(bv, bc);
#pragma unroll
      for (int off = 1; off <= 8; off <<= 1) {
        unsigned long long o = __shfl_xor(key, off, 64);
        if (o > key) key = o;
      }
      if (cl == 0 && gj < NH) atomicMax(&best[gj], key);
    }
}

__global__ __launch_bounds__(64) void k_out(const float* __restrict__ z,
                                            const int* __restrict__ src_idx,
                                            const unsigned long long* __restrict__ best,
                                            float* __restrict__ out,
                                            uint32_t ka0, uint32_t ka1) {
  int j = blockIdx.x;
  int lane = threadIdx.x;
  int s = src_idx[j];
  int tgt = (int)(~((uint32_t)(best[j] & 0xFFFFFFFFull)));
  uint32_t bits = rand32_at(ka0, ka1, (uint32_t)j);
  float alpha = unif01_from_bits(bits) * 0.5f;   // uniform * MIX_ALPHA
  float om = 1.0f - alpha;
  float4 a = *(const float4*)&z[s * DK + lane * 4];
  float4 b = *(const float4*)&z[tgt * DK + lane * 4];
  float4 o;
  o.x = alpha * a.x + om * b.x;
  o.y = alpha * a.y + om * b.y;
  o.z = alpha * a.z + om * b.z;
  o.w = alpha * a.w + om * b.w;
  *(float4*)&out[j * DK + lane * 4] = o;
}

// ---------------------------------------------------------------------------
extern "C" void kernel_launch(void* const* d_in, const int* in_sizes, int n_in,
                              void* d_out, int out_size, void* d_ws, size_t ws_size,
                              hipStream_t stream) {
  const float* z = (const float*)d_in[0];
  float* out = (float*)d_out;
  char* ws = (char*)d_ws;
  // ws layout (~16.8 MB):
  int*                src_idx = (int*)(ws);                        // 16 KB
  unsigned long long* best    = (unsigned long long*)(ws + 16384); // 32 KB
  unsigned short*     zh      = (unsigned short*)(ws + 65536);     // 8.39 MB
  unsigned short*     zl      = (unsigned short*)(ws + 65536 + 8388608);

  // host-side threefry key derivation (partitionable scheme, verified round 1)
  uint32_t r0 = 0u, r1 = 42u;
  uint32_t ks0, ks1, kt0, kt1, ka0, ka1, k20, k21;
  tf2x32(r0, r1, 0u, 0u, ks0, ks1);   // k_src   = split(root,3)[0]
  tf2x32(r0, r1, 0u, 1u, kt0, kt1);   // k_tgt   = split(root,3)[1]
  tf2x32(r0, r1, 0u, 2u, ka0, ka1);   // k_alpha = split(root,3)[2]
  tf2x32(ks0, ks1, 0u, 1u, k20, k21); // split(k_src,2)[1] (randint lower bits)

  k_prep<<<dim3(BN / 4 + (NH + 255) / 256), dim3(256), 0, stream>>>(
      z, zh, zl, src_idx, best, k20, k21);
  k_main<<<dim3(NCB * NJB), dim3(256), 0, stream>>>(zh, zl, src_idx, best, kt0, kt1);
  k_out <<<dim3(NH), dim3(64), 0, stream>>>(z, src_idx, best, out, ka0, ka1);
}